// Round 1
// baseline (1004.001 us; speedup 1.0000x reference)
//
#include <hip/hip_runtime.h>

// AggregateSet fused kernel, MI355X (gfx950).
// Shapes: B=1024, M_ELEM=128, D_IN=64, D_HID=256, H=8, D_K=D_V=64.
// Strategy: one block per batch, 4 waves. bf16 MFMA 16x16x32 everywhere.
//   GEMM1: activ[128][256] = xe(128x64) @ Wsub(64x256) + b  -> LDS (bf16, XOR-swizzled)
//   GEMM2: per wave, 2 heads; q,k accumulated in registers, score = in-lane
//          frag product + 16-lane shfl reduce; masked softmax in-wave;
//          v accumulated in registers, pooled via attn-weighted frag sum.
// K-permutation inside each MFMA uses the SAME formula for A and B fragments,
// so any error in the assumed per-lane K order cancels (sum over perm(k)).

typedef __attribute__((ext_vector_type(8))) short bf16x8;
typedef __attribute__((ext_vector_type(4))) float f32x4;

#define XROW 8320
#define MASK_OFF 8192

static __device__ __forceinline__ short f2bf(float f) {
  union { float f; unsigned u; } v; v.f = f;
  unsigned r = v.u + 0x7FFFu + ((v.u >> 16) & 1u);  // round-to-nearest-even
  return (short)(r >> 16);
}

static __device__ __forceinline__ f32x4 splat4(float v) {
  f32x4 r = {v, v, v, v};
  return r;
}

union BF8U { bf16x8 v; short4 s4[2]; };

// ---------------------------------------------------------------------------
// Weight prep: fp32 row-major W[k][n] -> bf16 transposed Wt[n][k] in d_ws.
//   Wt_sub [256][64]   @ elem 0
//   Wt_q   [512][256]  @ elem 16384
//   Wt_k   [512][256]  @ elem 147456
//   Wt_v   [512][256]  @ elem 278528
// total 409600 bf16 elems = 800 KB.
__global__ __launch_bounds__(256) void prep_weights(
    const float* __restrict__ Ws, const float* __restrict__ Wq,
    const float* __restrict__ Wk, const float* __restrict__ Wv,
    short* __restrict__ wt)
{
  int tid = blockIdx.x * 256 + threadIdx.x;   // grid is exactly 1600*256
  if (tid < 16384) {
    int n = tid >> 6, k = tid & 63;
    wt[tid] = f2bf(Ws[k * 256 + n]);
  } else {
    int idx = tid - 16384;
    int m = idx >> 17;            // 0:q 1:k 2:v
    int r = idx & 131071;
    int n = r >> 8, k = r & 255;
    const float* W = (m == 0) ? Wq : (m == 1) ? Wk : Wv;
    wt[tid] = f2bf(W[k * 512 + n]);
  }
}

// Load a B-fragment (KxN = 32x16) from transposed bf16 weights Wt[n][K].
// lane: n = nbase + (l&15); k = 32*ks + 4*(l>>4) + {0..3} and +16.
static __device__ __forceinline__ bf16x8 ld_w_frag(const short* __restrict__ w,
                                                   int n, int K, int ks, int lg) {
  BF8U t;
  const short* p = w + n * K + 32 * ks + 4 * lg;
  t.s4[0] = *(const short4*)p;
  t.s4[1] = *(const short4*)(p + 16);
  return t.v;
}

// Load an A-fragment (MxK = 16x32) from swizzled LDS activ.
// element (e, k) lives at activ[e*256 + ((k>>2 ^ (e&15))<<2) + (k&3)].
static __device__ __forceinline__ bf16x8 ld_a_frag(const short* activ,
                                                   int e, int ks, int lg) {
  BF8U t;
  const short* row = activ + e * 256;
  int u1 = ((8 * ks + lg) ^ (e & 15)) << 2;
  int u2 = ((8 * ks + lg + 4) ^ (e & 15)) << 2;
  t.s4[0] = *(const short4*)(row + u1);
  t.s4[1] = *(const short4*)(row + u2);
  return t.v;
}

__global__ __launch_bounds__(256, 2) void fused_kernel(
    const float* __restrict__ x,
    const float* __restrict__ bsub, const float* __restrict__ bq,
    const float* __restrict__ bk,   const float* __restrict__ bv,
    const short* __restrict__ wt,   float* __restrict__ out)
{
  __shared__ short activ[128 * 256];   // bf16, XOR-swizzled, exactly 64 KB

  const int b   = blockIdx.x;
  const int tid = threadIdx.x;
  const int w   = tid >> 6;       // wave 0..3
  const int l   = tid & 63;
  const int l15 = l & 15;
  const int lg  = l >> 4;

  const float* xb  = x + (size_t)b * XROW;
  const short* wts = wt;
  const short* wtq = wt + 16384;
  const short* wtk = wtq + 131072;
  const short* wtv = wtk + 131072;

  // ------------------- GEMM1: activ = xe @ Wsub + bsub -------------------
  // wave w owns rows 32w..32w+31 (2 m-tiles), all 256 cols.
  bf16x8 af1[2][2];
  #pragma unroll
  for (int mt = 0; mt < 2; ++mt) {
    #pragma unroll
    for (int ks = 0; ks < 2; ++ks) {
      int e  = 32 * w + 16 * mt + l15;
      int k0 = 32 * ks + 4 * lg;
      float4 f0 = *(const float4*)(xb + e * 64 + k0);
      float4 f1 = *(const float4*)(xb + e * 64 + k0 + 16);
      bf16x8 t;
      t[0] = f2bf(f0.x); t[1] = f2bf(f0.y); t[2] = f2bf(f0.z); t[3] = f2bf(f0.w);
      t[4] = f2bf(f1.x); t[5] = f2bf(f1.y); t[6] = f2bf(f1.z); t[7] = f2bf(f1.w);
      af1[mt][ks] = t;
    }
  }
  #pragma unroll
  for (int ntg = 0; ntg < 4; ++ntg) {
    f32x4 acc[2][4];
    #pragma unroll
    for (int nt = 0; nt < 4; ++nt) {
      float bias = bsub[64 * ntg + 16 * nt + l15];
      acc[0][nt] = splat4(bias);
      acc[1][nt] = splat4(bias);
    }
    #pragma unroll
    for (int ks = 0; ks < 2; ++ks) {
      bf16x8 bf[4];
      #pragma unroll
      for (int nt = 0; nt < 4; ++nt)
        bf[nt] = ld_w_frag(wts, 64 * ntg + 16 * nt + l15, 64, ks, lg);
      #pragma unroll
      for (int mt = 0; mt < 2; ++mt)
        #pragma unroll
        for (int nt = 0; nt < 4; ++nt)
          acc[mt][nt] = __builtin_amdgcn_mfma_f32_16x16x32_bf16(
              af1[mt][ks], bf[nt], acc[mt][nt], 0, 0, 0);
    }
    // write to swizzled LDS (C layout: row = 4*lg + r, col = l&15)
    #pragma unroll
    for (int mt = 0; mt < 2; ++mt) {
      #pragma unroll
      for (int nt = 0; nt < 4; ++nt) {
        int col = 64 * ntg + 16 * nt + l15;
        #pragma unroll
        for (int r = 0; r < 4; ++r) {
          int row = 32 * w + 16 * mt + 4 * lg + r;
          int idx = row * 256 + ((((col >> 2) ^ (row & 15)) << 2) | (col & 3));
          activ[idx] = f2bf(acc[mt][nt][r]);
        }
      }
    }
  }
  __syncthreads();

  // elem_frac (exact: mask is 0.0/1.0)
  if (tid == 0) {
    float s = 0.f;
    for (int e = 0; e < 128; ++e) s += xb[MASK_OFF + e];
    out[b * 513 + 512] = s * (1.f / 128.f);
  }

  // ------------------- per-head: q,k -> score -> softmax -> v -> pooled ---
  float p[8][4];  // per-lane scores/attn for e = 16*mt + 4*lg + r
  #pragma unroll
  for (int hi = 0; hi < 2; ++hi) {
    const int h = w + 4 * hi;

    // ---- qk phase: two mt-halves to bound register pressure ----
    #pragma unroll
    for (int half = 0; half < 2; ++half) {
      f32x4 aq[4][4], ak[4][4];
      #pragma unroll
      for (int nt = 0; nt < 4; ++nt) {
        float biq = bq[h * 64 + 16 * nt + l15];
        float bik = bk[h * 64 + 16 * nt + l15];
        #pragma unroll
        for (int mt = 0; mt < 4; ++mt) {
          aq[mt][nt] = splat4(biq);
          ak[mt][nt] = splat4(bik);
        }
      }
      #pragma unroll
      for (int ks = 0; ks < 8; ++ks) {
        bf16x8 af[4];
        #pragma unroll
        for (int mt = 0; mt < 4; ++mt)
          af[mt] = ld_a_frag(activ, 64 * half + 16 * mt + l15, ks, lg);
        bf16x8 bqf[4], bkf[4];
        #pragma unroll
        for (int nt = 0; nt < 4; ++nt) {
          int n = h * 64 + 16 * nt + l15;
          bqf[nt] = ld_w_frag(wtq, n, 256, ks, lg);
          bkf[nt] = ld_w_frag(wtk, n, 256, ks, lg);
        }
        #pragma unroll
        for (int mt = 0; mt < 4; ++mt) {
          #pragma unroll
          for (int nt = 0; nt < 4; ++nt) {
            aq[mt][nt] = __builtin_amdgcn_mfma_f32_16x16x32_bf16(
                af[mt], bqf[nt], aq[mt][nt], 0, 0, 0);
            ak[mt][nt] = __builtin_amdgcn_mfma_f32_16x16x32_bf16(
                af[mt], bkf[nt], ak[mt][nt], 0, 0, 0);
          }
        }
      }
      // score[e] = (q.k)/8 ; d-dim lives on l&15 -> 16-lane butterfly reduce
      #pragma unroll
      for (int mt = 0; mt < 4; ++mt) {
        #pragma unroll
        for (int r = 0; r < 4; ++r) {
          float s = 0.f;
          #pragma unroll
          for (int nt = 0; nt < 4; ++nt)
            s += aq[mt][nt][r] * ak[mt][nt][r];
          s += __shfl_xor(s, 1);
          s += __shfl_xor(s, 2);
          s += __shfl_xor(s, 4);
          s += __shfl_xor(s, 8);
          p[half * 4 + mt][r] = s * 0.125f;
        }
      }
    }

    // ---- masked softmax over 128 elems (whole head in this wave) ----
    float zmax = 0.f;  // relu(z*m) includes 0 floor
    #pragma unroll
    for (int mt = 0; mt < 8; ++mt)
      #pragma unroll
      for (int r = 0; r < 4; ++r) {
        float m = xb[MASK_OFF + 16 * mt + 4 * lg + r];
        zmax = fmaxf(zmax, (m > 0.f) ? p[mt][r] : 0.f);
      }
    zmax = fmaxf(zmax, __shfl_xor(zmax, 16));
    zmax = fmaxf(zmax, __shfl_xor(zmax, 32));
    float esum = 0.f;
    #pragma unroll
    for (int mt = 0; mt < 8; ++mt)
      #pragma unroll
      for (int r = 0; r < 4; ++r) {
        float m  = xb[MASK_OFF + 16 * mt + 4 * lg + r];
        float ev = (m > 0.f) ? __expf(p[mt][r] - zmax) : 0.f;
        p[mt][r] = ev;
        esum += ev;
      }
    esum += __shfl_xor(esum, 16);
    esum += __shfl_xor(esum, 32);
    float inv = 1.f / (esum + 1.f);
    #pragma unroll
    for (int mt = 0; mt < 8; ++mt)
      #pragma unroll
      for (int r = 0; r < 4; ++r) p[mt][r] *= inv;

    // ---- v phase + pooled, two mt-halves ----
    float pp[4] = {0.f, 0.f, 0.f, 0.f};
    #pragma unroll
    for (int half = 0; half < 2; ++half) {
      f32x4 av[4][4];
      #pragma unroll
      for (int nt = 0; nt < 4; ++nt) {
        float biv = bv[h * 64 + 16 * nt + l15];
        #pragma unroll
        for (int mt = 0; mt < 4; ++mt) av[mt][nt] = splat4(biv);
      }
      #pragma unroll
      for (int ks = 0; ks < 8; ++ks) {
        bf16x8 af[4];
        #pragma unroll
        for (int mt = 0; mt < 4; ++mt)
          af[mt] = ld_a_frag(activ, 64 * half + 16 * mt + l15, ks, lg);
        bf16x8 bvf[4];
        #pragma unroll
        for (int nt = 0; nt < 4; ++nt)
          bvf[nt] = ld_w_frag(wtv, h * 64 + 16 * nt + l15, 256, ks, lg);
        #pragma unroll
        for (int mt = 0; mt < 4; ++mt)
          #pragma unroll
          for (int nt = 0; nt < 4; ++nt)
            av[mt][nt] = __builtin_amdgcn_mfma_f32_16x16x32_bf16(
                af[mt], bvf[nt], av[mt][nt], 0, 0, 0);
      }
      #pragma unroll
      for (int nt = 0; nt < 4; ++nt) {
        float s = 0.f;
        #pragma unroll
        for (int mt = 0; mt < 4; ++mt)
          #pragma unroll
          for (int r = 0; r < 4; ++r)
            s += p[half * 4 + mt][r] * av[mt][nt][r];
        pp[nt] += s;
      }
    }
    // reduce over the 4 lane-groups (e-subsets); d = 16*nt + l&15
    #pragma unroll
    for (int nt = 0; nt < 4; ++nt) {
      float s = pp[nt];
      s += __shfl_xor(s, 16);
      s += __shfl_xor(s, 32);
      if (l < 16) out[b * 513 + h * 64 + 16 * nt + l15] = s;
    }
  }
}

extern "C" void kernel_launch(void* const* d_in, const int* in_sizes, int n_in,
                              void* d_out, int out_size, void* d_ws, size_t ws_size,
                              hipStream_t stream) {
  (void)in_sizes; (void)n_in; (void)out_size; (void)ws_size;
  const float* x    = (const float*)d_in[0];
  const float* Wsub = (const float*)d_in[1];
  const float* bsub = (const float*)d_in[2];
  const float* Wq   = (const float*)d_in[3];
  const float* bq   = (const float*)d_in[4];
  const float* Wk   = (const float*)d_in[5];
  const float* bk   = (const float*)d_in[6];
  const float* Wv   = (const float*)d_in[7];
  const float* bv   = (const float*)d_in[8];
  float* out = (float*)d_out;
  short* wt  = (short*)d_ws;   // 800 KB used

  prep_weights<<<1600, 256, 0, stream>>>(Wsub, Wq, Wk, Wv, wt);
  fused_kernel<<<1024, 256, 0, stream>>>(x, bsub, bq, bk, bv, wt, out);
}

// Round 2
// 294.373 us; speedup vs baseline: 3.4106x; 3.4106x over previous
//
#include <hip/hip_runtime.h>

// AggregateSet fused kernel, MI355X (gfx950).
// Shapes: B=1024, M_ELEM=128, D_IN=64, D_HID=256, H=8, D_K=D_V=64.
// R1: de-spill GEMM2. R0 spilled ~1.6 GB to scratch (WRITE_SIZE evidence):
// aq[4][4]+ak[4][4] accumulators + unrolled hi loop exceeded the 256-VGPR
// budget. Now: d-dim processed in nt-PAIRS (aq[2][8]+ak[2][8] = 128 VGPR),
// outer loops #pragma unroll 1, q.k partial dot folded after each pair.
// Mask staged to LDS once per block.

typedef __attribute__((ext_vector_type(8))) short bf16x8;
typedef __attribute__((ext_vector_type(4))) float f32x4;

#define XROW 8320
#define MASK_OFF 8192

static __device__ __forceinline__ short f2bf(float f) {
  union { float f; unsigned u; } v; v.f = f;
  unsigned r = v.u + 0x7FFFu + ((v.u >> 16) & 1u);  // round-to-nearest-even
  return (short)(r >> 16);
}

static __device__ __forceinline__ f32x4 splat4(float v) {
  f32x4 r = {v, v, v, v};
  return r;
}

union BF8U { bf16x8 v; short4 s4[2]; };

// ---------------------------------------------------------------------------
// Weight prep: fp32 row-major W[k][n] -> bf16 transposed Wt[n][k] in d_ws.
__global__ __launch_bounds__(256) void prep_weights(
    const float* __restrict__ Ws, const float* __restrict__ Wq,
    const float* __restrict__ Wk, const float* __restrict__ Wv,
    short* __restrict__ wt)
{
  int tid = blockIdx.x * 256 + threadIdx.x;   // grid is exactly 1600*256
  if (tid < 16384) {
    int n = tid >> 6, k = tid & 63;
    wt[tid] = f2bf(Ws[k * 256 + n]);
  } else {
    int idx = tid - 16384;
    int m = idx >> 17;            // 0:q 1:k 2:v
    int r = idx & 131071;
    int n = r >> 8, k = r & 255;
    const float* W = (m == 0) ? Wq : (m == 1) ? Wk : Wv;
    wt[tid] = f2bf(W[k * 512 + n]);
  }
}

// B-fragment (KxN = 32x16) from transposed bf16 weights Wt[n][K].
static __device__ __forceinline__ bf16x8 ld_w_frag(const short* __restrict__ w,
                                                   int n, int K, int ks, int lg) {
  BF8U t;
  const short* p = w + n * K + 32 * ks + 4 * lg;
  t.s4[0] = *(const short4*)p;
  t.s4[1] = *(const short4*)(p + 16);
  return t.v;
}

// A-fragment (MxK = 16x32) from swizzled LDS activ.
// element (e, k) lives at activ[e*256 + ((k>>2 ^ (e&15))<<2) + (k&3)].
static __device__ __forceinline__ bf16x8 ld_a_frag(const short* activ,
                                                   int e, int ks, int lg) {
  BF8U t;
  const short* row = activ + e * 256;
  int u1 = ((8 * ks + lg) ^ (e & 15)) << 2;
  int u2 = ((8 * ks + lg + 4) ^ (e & 15)) << 2;
  t.s4[0] = *(const short4*)(row + u1);
  t.s4[1] = *(const short4*)(row + u2);
  return t.v;
}

__global__ __launch_bounds__(256, 2) void fused_kernel(
    const float* __restrict__ x,
    const float* __restrict__ bsub, const float* __restrict__ bq,
    const float* __restrict__ bk,   const float* __restrict__ bv,
    const short* __restrict__ wt,   float* __restrict__ out)
{
  __shared__ short activ[128 * 256];   // bf16, XOR-swizzled, 64 KB
  __shared__ float smask[128];

  const int b   = blockIdx.x;
  const int tid = threadIdx.x;
  const int w   = tid >> 6;       // wave 0..3
  const int l   = tid & 63;
  const int l15 = l & 15;
  const int lg  = l >> 4;

  const float* xb  = x + (size_t)b * XROW;
  const short* wts = wt;
  const short* wtq = wt + 16384;
  const short* wtk = wtq + 131072;
  const short* wtv = wtk + 131072;

  if (tid < 128) smask[tid] = xb[MASK_OFF + tid];

  // ------------------- GEMM1: activ = xe @ Wsub + bsub -------------------
  // wave w owns rows 32w..32w+31 (2 m-tiles), all 256 cols.
  bf16x8 af1[2][2];
  #pragma unroll
  for (int mt = 0; mt < 2; ++mt) {
    #pragma unroll
    for (int ks = 0; ks < 2; ++ks) {
      int e  = 32 * w + 16 * mt + l15;
      int k0 = 32 * ks + 4 * lg;
      float4 f0 = *(const float4*)(xb + e * 64 + k0);
      float4 f1 = *(const float4*)(xb + e * 64 + k0 + 16);
      bf16x8 t;
      t[0] = f2bf(f0.x); t[1] = f2bf(f0.y); t[2] = f2bf(f0.z); t[3] = f2bf(f0.w);
      t[4] = f2bf(f1.x); t[5] = f2bf(f1.y); t[6] = f2bf(f1.z); t[7] = f2bf(f1.w);
      af1[mt][ks] = t;
    }
  }
  #pragma unroll 1
  for (int ntg = 0; ntg < 4; ++ntg) {
    f32x4 acc[2][4];
    #pragma unroll
    for (int nt = 0; nt < 4; ++nt) {
      float bias = bsub[64 * ntg + 16 * nt + l15];
      acc[0][nt] = splat4(bias);
      acc[1][nt] = splat4(bias);
    }
    #pragma unroll
    for (int ks = 0; ks < 2; ++ks) {
      bf16x8 bf[4];
      #pragma unroll
      for (int nt = 0; nt < 4; ++nt)
        bf[nt] = ld_w_frag(wts, 64 * ntg + 16 * nt + l15, 64, ks, lg);
      #pragma unroll
      for (int mt = 0; mt < 2; ++mt)
        #pragma unroll
        for (int nt = 0; nt < 4; ++nt)
          acc[mt][nt] = __builtin_amdgcn_mfma_f32_16x16x32_bf16(
              af1[mt][ks], bf[nt], acc[mt][nt], 0, 0, 0);
    }
    // write to swizzled LDS (C layout: row = 4*lg + r, col = l&15)
    #pragma unroll
    for (int mt = 0; mt < 2; ++mt) {
      #pragma unroll
      for (int nt = 0; nt < 4; ++nt) {
        int col = 64 * ntg + 16 * nt + l15;
        #pragma unroll
        for (int r = 0; r < 4; ++r) {
          int row = 32 * w + 16 * mt + 4 * lg + r;
          int idx = row * 256 + ((((col >> 2) ^ (row & 15)) << 2) | (col & 3));
          activ[idx] = f2bf(acc[mt][nt][r]);
        }
      }
    }
  }
  __syncthreads();

  // elem_frac (exact: mask is 0.0/1.0) — wave 0, parallel
  if (tid < 64) {
    float s = smask[tid] + smask[tid + 64];
    #pragma unroll
    for (int off = 32; off > 0; off >>= 1) s += __shfl_xor(s, off);
    if (tid == 0) out[b * 513 + 512] = s * (1.f / 128.f);
  }

  // ------------------- per-head: q,k -> score -> softmax -> v -> pooled ---
  #pragma unroll 1
  for (int hi = 0; hi < 2; ++hi) {
    const int h = w + 4 * hi;

    float p[8][4];   // per-lane partial q.k for e = 16*mt + 4*lg + r
    #pragma unroll
    for (int mt = 0; mt < 8; ++mt)
      #pragma unroll
      for (int r = 0; r < 4; ++r) p[mt][r] = 0.f;

    // ---- qk phase: d-dim in pairs of 16 (nt-pair) to bound registers ----
    #pragma unroll 1
    for (int ntp = 0; ntp < 2; ++ntp) {
      f32x4 aq[2][8], ak[2][8];
      #pragma unroll
      for (int nn = 0; nn < 2; ++nn) {
        float biq = bq[h * 64 + 32 * ntp + 16 * nn + l15];
        float bik = bk[h * 64 + 32 * ntp + 16 * nn + l15];
        #pragma unroll
        for (int mt = 0; mt < 8; ++mt) {
          aq[nn][mt] = splat4(biq);
          ak[nn][mt] = splat4(bik);
        }
      }
      #pragma unroll 1
      for (int ks = 0; ks < 8; ++ks) {
        bf16x8 bqf[2], bkf[2];
        #pragma unroll
        for (int nn = 0; nn < 2; ++nn) {
          int n = h * 64 + 32 * ntp + 16 * nn + l15;
          bqf[nn] = ld_w_frag(wtq, n, 256, ks, lg);
          bkf[nn] = ld_w_frag(wtk, n, 256, ks, lg);
        }
        #pragma unroll
        for (int mt = 0; mt < 8; ++mt) {
          bf16x8 af = ld_a_frag(activ, 16 * mt + l15, ks, lg);
          #pragma unroll
          for (int nn = 0; nn < 2; ++nn) {
            aq[nn][mt] = __builtin_amdgcn_mfma_f32_16x16x32_bf16(
                af, bqf[nn], aq[nn][mt], 0, 0, 0);
            ak[nn][mt] = __builtin_amdgcn_mfma_f32_16x16x32_bf16(
                af, bkf[nn], ak[nn][mt], 0, 0, 0);
          }
        }
      }
      // fold partial dot over this 32-wide d-chunk into p
      #pragma unroll
      for (int mt = 0; mt < 8; ++mt)
        #pragma unroll
        for (int r = 0; r < 4; ++r) {
          float s = aq[0][mt][r] * ak[0][mt][r] + aq[1][mt][r] * ak[1][mt][r];
          p[mt][r] += s;
        }
    }
    // reduce over the 16 d-lanes and scale by 1/sqrt(64)
    #pragma unroll
    for (int mt = 0; mt < 8; ++mt)
      #pragma unroll
      for (int r = 0; r < 4; ++r) {
        float s = p[mt][r];
        s += __shfl_xor(s, 1);
        s += __shfl_xor(s, 2);
        s += __shfl_xor(s, 4);
        s += __shfl_xor(s, 8);
        p[mt][r] = s * 0.125f;
      }

    // ---- masked softmax over 128 elems (whole head in this wave) ----
    float zmax = 0.f;  // relu floor
    #pragma unroll
    for (int mt = 0; mt < 8; ++mt)
      #pragma unroll
      for (int r = 0; r < 4; ++r) {
        float m = smask[16 * mt + 4 * lg + r];
        zmax = fmaxf(zmax, (m > 0.f) ? p[mt][r] : 0.f);
      }
    zmax = fmaxf(zmax, __shfl_xor(zmax, 16));
    zmax = fmaxf(zmax, __shfl_xor(zmax, 32));
    float esum = 0.f;
    #pragma unroll
    for (int mt = 0; mt < 8; ++mt)
      #pragma unroll
      for (int r = 0; r < 4; ++r) {
        float m  = smask[16 * mt + 4 * lg + r];
        float ev = (m > 0.f) ? __expf(p[mt][r] - zmax) : 0.f;
        p[mt][r] = ev;
        esum += ev;
      }
    esum += __shfl_xor(esum, 16);
    esum += __shfl_xor(esum, 32);
    float inv = 1.f / (esum + 1.f);
    #pragma unroll
    for (int mt = 0; mt < 8; ++mt)
      #pragma unroll
      for (int r = 0; r < 4; ++r) p[mt][r] *= inv;

    // ---- v phase + pooled, d-dim in nt-pairs ----
    float pp0, pp1, pp2, pp3;
    #pragma unroll 1
    for (int ntp = 0; ntp < 2; ++ntp) {
      f32x4 av[2][8];
      #pragma unroll
      for (int nn = 0; nn < 2; ++nn) {
        float biv = bv[h * 64 + 32 * ntp + 16 * nn + l15];
        #pragma unroll
        for (int mt = 0; mt < 8; ++mt) av[nn][mt] = splat4(biv);
      }
      #pragma unroll 1
      for (int ks = 0; ks < 8; ++ks) {
        bf16x8 bvf[2];
        #pragma unroll
        for (int nn = 0; nn < 2; ++nn)
          bvf[nn] = ld_w_frag(wtv, h * 64 + 32 * ntp + 16 * nn + l15, 256, ks, lg);
        #pragma unroll
        for (int mt = 0; mt < 8; ++mt) {
          bf16x8 af = ld_a_frag(activ, 16 * mt + l15, ks, lg);
          #pragma unroll
          for (int nn = 0; nn < 2; ++nn)
            av[nn][mt] = __builtin_amdgcn_mfma_f32_16x16x32_bf16(
                af, bvf[nn], av[nn][mt], 0, 0, 0);
        }
      }
      #pragma unroll
      for (int nn = 0; nn < 2; ++nn) {
        float s = 0.f;
        #pragma unroll
        for (int mt = 0; mt < 8; ++mt)
          #pragma unroll
          for (int r = 0; r < 4; ++r)
            s += p[mt][r] * av[nn][mt][r];
        // keep destination indices compile-time-constant (no scratch)
        if (ntp == 0) { if (nn == 0) pp0 = s; else pp1 = s; }
        else          { if (nn == 0) pp2 = s; else pp3 = s; }
      }
    }
    // reduce over the 4 lane-groups; write d = 16*nt + l&15
    #pragma unroll
    for (int nt = 0; nt < 4; ++nt) {
      float s = (nt == 0) ? pp0 : (nt == 1) ? pp1 : (nt == 2) ? pp2 : pp3;
      s += __shfl_xor(s, 16);
      s += __shfl_xor(s, 32);
      if (l < 16) out[b * 513 + h * 64 + 16 * nt + l15] = s;
    }
  }
}

extern "C" void kernel_launch(void* const* d_in, const int* in_sizes, int n_in,
                              void* d_out, int out_size, void* d_ws, size_t ws_size,
                              hipStream_t stream) {
  (void)in_sizes; (void)n_in; (void)out_size; (void)ws_size;
  const float* x    = (const float*)d_in[0];
  const float* Wsub = (const float*)d_in[1];
  const float* bsub = (const float*)d_in[2];
  const float* Wq   = (const float*)d_in[3];
  const float* bq   = (const float*)d_in[4];
  const float* Wk   = (const float*)d_in[5];
  const float* bk   = (const float*)d_in[6];
  const float* Wv   = (const float*)d_in[7];
  const float* bv   = (const float*)d_in[8];
  float* out = (float*)d_out;
  short* wt  = (short*)d_ws;   // 800 KB used

  prep_weights<<<1600, 256, 0, stream>>>(Wsub, Wq, Wk, Wv, wt);
  fused_kernel<<<1024, 256, 0, stream>>>(x, bsub, bq, bk, bv, wt, out);
}